// Round 2
// baseline (244.898 us; speedup 1.0000x reference)
//
#include <hip/hip_runtime.h>
#include <math.h>

typedef __bf16 bf16;
typedef __bf16 bf16x8 __attribute__((ext_vector_type(8)));
typedef float f32x4 __attribute__((ext_vector_type(4)));
typedef unsigned int u32;

#define MFMA_BF16(a, b, c) __builtin_amdgcn_mfma_f32_16x16x32_bf16((a), (b), (c), 0, 0, 0)

static constexpr int kB = 2;
static constexpr int kS = 2048;
static constexpr int kD = 512;
static constexpr int kH = 8;
static constexpr int kDK = 64;
static constexpr int kPR = 16 * kS;  // partial rows per split (bh*q)

// ---------------- mask dtype detection (bool-1B vs int32) ----------------
__global__ void detect_mask_kernel(const unsigned char* __restrict__ m,
                                   unsigned int* __restrict__ flag) {
  __shared__ int sh;
  if (threadIdx.x == 0) sh = 0;
  __syncthreads();
  int any = 0;
  for (int i = threadIdx.x; i < kB * kS; i += 256)
    if ((i & 3) != 0 && m[i] != 0) any = 1;
  if (any) atomicOr(&sh, 1);
  __syncthreads();
  if (threadIdx.x == 0) *flag = (unsigned int)sh;
}

// ---------------- helpers ----------------
__device__ __forceinline__ void cvt16(const float* __restrict__ p, bf16x8& v0, bf16x8& v1) {
  const float4 fA = ((const float4*)p)[0];
  const float4 fB = ((const float4*)p)[1];
  const float4 fC = ((const float4*)p)[2];
  const float4 fD = ((const float4*)p)[3];
  v0[0] = (bf16)fA.x; v0[1] = (bf16)fA.y; v0[2] = (bf16)fA.z; v0[3] = (bf16)fA.w;
  v0[4] = (bf16)fB.x; v0[5] = (bf16)fB.y; v0[6] = (bf16)fB.z; v0[7] = (bf16)fB.w;
  v1[0] = (bf16)fC.x; v1[1] = (bf16)fC.y; v1[2] = (bf16)fC.z; v1[3] = (bf16)fC.w;
  v1[4] = (bf16)fD.x; v1[5] = (bf16)fD.y; v1[6] = (bf16)fD.z; v1[7] = (bf16)fD.w;
}

// ---------------- GEMM: C[m][n] = sum_k A[m][k] * W[n][k] ----------------
template <bool A_IS_F32>
__device__ __forceinline__ void gemm_body(const void* __restrict__ Aptr,
                                          const float* __restrict__ Wptr,
                                          void* __restrict__ dst, const int mode) {
  __shared__ bf16 As[128][40];
  __shared__ bf16 Bs[128][40];

  const int tid = threadIdx.x;
  const int lane = tid & 63;
  const int w = tid >> 6;
  const int wr = w >> 1, wc = w & 1;
  const int l16 = lane & 15, g = lane >> 4;

  const int m_tile = blockIdx.x * 128;
  const int n_tile = blockIdx.y * 128;

  f32x4 acc[4][4] = {};

  const int sr = tid >> 1;
  const int sc = (tid & 1) * 16;

  for (int k0 = 0; k0 < kD; k0 += 32) {
    if constexpr (A_IS_F32) {
      const float* ap = (const float*)Aptr + (size_t)(m_tile + sr) * kD + k0 + sc;
      bf16x8 v0, v1;
      cvt16(ap, v0, v1);
      *(bf16x8*)&As[sr][sc] = v0;
      *(bf16x8*)&As[sr][sc + 8] = v1;
    } else {
      const bf16* ap = (const bf16*)Aptr + (size_t)(m_tile + sr) * kD + k0 + sc;
      *(bf16x8*)&As[sr][sc] = *(const bf16x8*)ap;
      *(bf16x8*)&As[sr][sc + 8] = *(const bf16x8*)(ap + 8);
    }
    {
      const float* bp = Wptr + (size_t)(n_tile + sr) * kD + k0 + sc;
      bf16x8 v0, v1;
      cvt16(bp, v0, v1);
      *(bf16x8*)&Bs[sr][sc] = v0;
      *(bf16x8*)&Bs[sr][sc + 8] = v1;
    }
    __syncthreads();

    bf16x8 a[4], bfr[4];
    #pragma unroll
    for (int i = 0; i < 4; i++)
      a[i] = *(const bf16x8*)&As[wr * 64 + i * 16 + l16][g * 8];
    #pragma unroll
    for (int i = 0; i < 4; i++)
      bfr[i] = *(const bf16x8*)&Bs[wc * 64 + i * 16 + l16][g * 8];
    #pragma unroll
    for (int mi = 0; mi < 4; mi++)
      #pragma unroll
      for (int ni = 0; ni < 4; ni++)
        acc[mi][ni] = MFMA_BF16(a[mi], bfr[ni], acc[mi][ni]);
    __syncthreads();
  }

  #pragma unroll
  for (int mi = 0; mi < 4; mi++) {
    #pragma unroll
    for (int ni = 0; ni < 4; ni++) {
      const int gm0 = m_tile + wr * 64 + mi * 16 + g * 4;
      const int gn = n_tile + wc * 64 + ni * 16 + l16;
      #pragma unroll
      for (int q = 0; q < 4; q++) {
        const int gm = gm0 + q;
        const float v = acc[mi][ni][q];
        if (mode == 3) {
          ((float*)dst)[(size_t)gm * kD + gn] = v;
        } else {
          const int bi = gm >> 11;
          const int s = gm & (kS - 1);
          const int h = gn >> 6;
          const int dk = gn & (kDK - 1);
          if (mode == 2)
            ((bf16*)dst)[(((size_t)bi * kH + h) * kDK + dk) * kS + s] = (bf16)v;
          else
            ((bf16*)dst)[(((size_t)bi * kH + h) * kS + s) * kDK + dk] = (bf16)v;
        }
      }
    }
  }
}

__global__ __launch_bounds__(256) void proj_kernel(
    const float* __restrict__ q, const float* __restrict__ k, const float* __restrict__ v,
    const float* __restrict__ Wq, const float* __restrict__ Wk, const float* __restrict__ Wv,
    bf16* __restrict__ qw, bf16* __restrict__ kw, bf16* __restrict__ vtw) {
  const int z = blockIdx.z;
  const float* A = (z == 0) ? q : (z == 1) ? k : v;
  const float* W = (z == 0) ? Wq : (z == 1) ? Wk : Wv;
  bf16* dstp = (z == 0) ? qw : (z == 1) ? kw : vtw;
  gemm_body<true>(A, W, dstp, (z == 2) ? 2 : 0);
}

__global__ __launch_bounds__(256) void out_kernel(const bf16* __restrict__ x,
                                                  const float* __restrict__ Wo,
                                                  float* __restrict__ out) {
  gemm_body<false>(x, Wo, out, 3);
}

// ---------------- attention (swapped-operand, split-K, no block barriers) ----
// grid (32, 16, NS), 256 thr. Wave w: q-tile blockIdx.x*4+w (16 rows), keys
// [z*kseg, (z+1)*kseg). Swapped QK^T: lane holds P[k=nf*16+g*4+r][q=l16].
__global__ __launch_bounds__(256) void attn_kernel(
    const bf16* __restrict__ qw, const bf16* __restrict__ kw,
    const bf16* __restrict__ vt, const float* __restrict__ bias,
    const unsigned char* __restrict__ maskp, const unsigned int* __restrict__ flagp,
    float* __restrict__ Opart, float* __restrict__ Mpart, float* __restrict__ Lpart,
    const int kseg) {
  __shared__ u32 Ps[4][16][36];  // per-wave packed P^T rows: [q][k/2], pad 36

  const int tid = threadIdx.x;
  const int lane = tid & 63;
  const int w = tid >> 6;
  const int l16 = lane & 15, g = lane >> 4;

  const int bh = blockIdx.y;
  const int b = bh >> 3;
  const int qr0 = (blockIdx.x * 4 + w) * 16;
  const int ks0 = blockIdx.z * kseg;

  const bool as_bool = (*flagp != 0u);

  // Q as B operand: col=q=l16, k = g*8+j
  const bf16* qrow = qw + ((size_t)bh * kS + qr0 + l16) * kDK;
  const bf16x8 aq0 = *(const bf16x8*)(qrow + g * 8);
  const bf16x8 aq1 = *(const bf16x8*)(qrow + 32 + g * 8);

  const float* brow = bias + ((size_t)bh * kS + qr0 + l16) * kS;  // bias row q=l16
  const bf16* kbase = kw + (size_t)bh * kS * kDK;
  const bf16* vbase = vt + (size_t)bh * kDK * kS;

  f32x4 o[4] = {};           // O^T: row d = ni*16+g*4+r, col q = l16
  float m_run = -__builtin_inff();
  float l_run = 0.f;

  for (int k0 = ks0; k0 < ks0 + kseg; k0 += 64) {
    // ---- bias + mask for this tile (coalesced float4) ----
    float4 bv[4];
    #pragma unroll
    for (int nf = 0; nf < 4; nf++)
      bv[nf] = *(const float4*)(brow + k0 + nf * 16 + g * 4);

    int mvals[4][4];
    if (as_bool) {
      #pragma unroll
      for (int nf = 0; nf < 4; nf++) {
        const uchar4 mc = *(const uchar4*)(maskp + (size_t)b * kS + k0 + nf * 16 + g * 4);
        mvals[nf][0] = mc.x; mvals[nf][1] = mc.y; mvals[nf][2] = mc.z; mvals[nf][3] = mc.w;
      }
    } else {
      #pragma unroll
      for (int nf = 0; nf < 4; nf++) {
        const int4 mi4 = *(const int4*)((const int*)maskp + (size_t)b * kS + k0 + nf * 16 + g * 4);
        mvals[nf][0] = mi4.x; mvals[nf][1] = mi4.y; mvals[nf][2] = mi4.z; mvals[nf][3] = mi4.w;
      }
    }

    // ---- K fragments (A operand: row=k=l16-within-block, k-dim = dk) ----
    bf16x8 kf[4][2];
    #pragma unroll
    for (int nf = 0; nf < 4; nf++) {
      const bf16* kp = kbase + (size_t)(k0 + nf * 16 + l16) * kDK + g * 8;
      kf[nf][0] = *(const bf16x8*)kp;
      kf[nf][1] = *(const bf16x8*)(kp + 32);
    }

    // ---- QK^T swapped: C[k][q] ----
    f32x4 sf[4];
    #pragma unroll
    for (int nf = 0; nf < 4; nf++) {
      f32x4 z = {};
      z = MFMA_BF16(kf[nf][0], aq0, z);
      z = MFMA_BF16(kf[nf][1], aq1, z);
      sf[nf] = z;
    }

    // ---- V fragments for PV (A operand: row=d, k-dim=key), issued early ----
    bf16x8 vf[2][4];
    #pragma unroll
    for (int kb = 0; kb < 2; kb++)
      #pragma unroll
      for (int ni = 0; ni < 4; ni++)
        vf[kb][ni] = *(const bf16x8*)(vbase + (size_t)(ni * 16 + l16) * kS + k0 + kb * 32 + g * 8);

    // ---- scores: scale, mask, bias; per-lane online softmax (q = l16) ----
    float p[4][4];
    float tmax = -__builtin_inff();
    #pragma unroll
    for (int nf = 0; nf < 4; nf++) {
      #pragma unroll
      for (int r = 0; r < 4; r++) {
        float sv = sf[nf][r] * 0.125f - ((const float*)&bv[nf])[r];
        if (mvals[nf][r] != 0) sv = -__builtin_inff();
        p[nf][r] = sv;
        tmax = fmaxf(tmax, sv);
      }
    }
    tmax = fmaxf(tmax, __shfl_xor(tmax, 16, 64));
    tmax = fmaxf(tmax, __shfl_xor(tmax, 32, 64));

    const float mnew = fmaxf(m_run, tmax);
    const float scale = (m_run == -__builtin_inff()) ? 0.f : __expf(m_run - mnew);
    const float mexp = (mnew == -__builtin_inff()) ? 0.f : mnew;
    float psum = 0.f;
    #pragma unroll
    for (int nf = 0; nf < 4; nf++)
      #pragma unroll
      for (int r = 0; r < 4; r++) {
        const float pv = __expf(p[nf][r] - mexp);
        p[nf][r] = pv;
        psum += pv;
      }
    psum += __shfl_xor(psum, 16, 64);
    psum += __shfl_xor(psum, 32, 64);
    m_run = mnew;
    l_run = l_run * scale + psum;
    #pragma unroll
    for (int ni = 0; ni < 4; ni++) o[ni] *= scale;

    // ---- P^T pack to LDS: row q=l16, u32 col = k/2 ----
    #pragma unroll
    for (int nf = 0; nf < 4; nf++) {
      union { bf16 h[2]; u32 u; } c0, c1;
      c0.h[0] = (bf16)p[nf][0]; c0.h[1] = (bf16)p[nf][1];
      c1.h[0] = (bf16)p[nf][2]; c1.h[1] = (bf16)p[nf][3];
      Ps[w][l16][nf * 8 + g * 2] = c0.u;
      Ps[w][l16][nf * 8 + g * 2 + 1] = c1.u;
    }
    asm volatile("s_waitcnt lgkmcnt(0)" ::: "memory");

    // ---- PV: O^T += V^T * P^T ----
    #pragma unroll
    for (int kb = 0; kb < 2; kb++) {
      const bf16x8 pb = *(const bf16x8*)&Ps[w][l16][kb * 16 + g * 4];
      #pragma unroll
      for (int ni = 0; ni < 4; ni++)
        o[ni] = MFMA_BF16(vf[kb][ni], pb, o[ni]);
    }
  }

  // ---- write partials: row = ((z*16+bh)*2048 + qr0+l16), d consecutive ----
  const size_t prow = ((size_t)blockIdx.z * 16 + bh) * kS + qr0 + l16;
  #pragma unroll
  for (int ni = 0; ni < 4; ni++)
    *(float4*)&Opart[prow * kDK + ni * 16 + g * 4] = (float4){o[ni][0], o[ni][1], o[ni][2], o[ni][3]};
  if (g == 0) {
    Mpart[prow] = m_run;
    Lpart[prow] = l_run;
  }
}

// ---------------- combine splits -> x_ws (bf16 [b][s][h*64+d]) ----------------
__global__ __launch_bounds__(256) void combine_kernel(
    const float* __restrict__ Opart, const float* __restrict__ Mpart,
    const float* __restrict__ Lpart, bf16* __restrict__ xw, const int NS) {
  const int idx = blockIdx.x * 256 + threadIdx.x;  // 16*2048*64 total
  const int d = idx & 63;
  const int row = idx >> 6;  // bh*2048 + q
  const int bh = row >> 11, q = row & (kS - 1);
  const int b = bh >> 3, h = bh & 7;

  float M = -__builtin_inff();
  for (int s = 0; s < NS; s++) M = fmaxf(M, Mpart[s * kPR + row]);

  float acc = 0.f, L = 0.f;
  if (M != -__builtin_inff()) {
    for (int s = 0; s < NS; s++) {
      const float ms = Mpart[s * kPR + row];
      if (ms != -__builtin_inff()) {
        const float wgt = __expf(ms - M);
        L += wgt * Lpart[s * kPR + row];
        acc += wgt * Opart[((size_t)s * kPR + row) * kDK + d];
      }
    }
  }
  const float inv = (L > 0.f) ? 1.f / L : 0.f;
  xw[((size_t)b * kS + q) * kD + h * kDK + d] = (bf16)(acc * inv);
}

extern "C" void kernel_launch(void* const* d_in, const int* in_sizes, int n_in,
                              void* d_out, int out_size, void* d_ws, size_t ws_size,
                              hipStream_t stream) {
  (void)in_sizes; (void)n_in; (void)out_size;
  const float* query = (const float*)d_in[0];
  const float* key_in = (const float*)d_in[1];
  const float* value = (const float*)d_in[2];
  const float* attnw = (const float*)d_in[3];
  const unsigned char* mask = (const unsigned char*)d_in[4];
  const float* Wq = (const float*)d_in[5];
  const float* Wk = (const float*)d_in[6];
  const float* Wv = (const float*)d_in[7];
  const float* Wo = (const float*)d_in[8];

  const size_t nqkv = (size_t)kB * kH * kS * kDK;  // 2M elems
  size_t off = 0;
  auto alloc = [&](size_t bytes) {
    void* p = (char*)d_ws + off;
    off = (off + bytes + 255) & ~(size_t)255;
    return p;
  };
  unsigned int* flagp = (unsigned int*)alloc(4);
  bf16* q_ws = (bf16*)alloc(nqkv * 2);
  bf16* k_ws = (bf16*)alloc(nqkv * 2);
  bf16* vt_ws = (bf16*)alloc(nqkv * 2);
  bf16* x_ws = (bf16*)alloc((size_t)kB * kS * kD * 2);
  const size_t fixed = off;
  const size_t per_split = ((size_t)kPR * kDK + 2 * kPR) * 4 + 1024;
  int NS = 1;
  if (fixed + 4 * per_split <= ws_size) NS = 4;
  else if (fixed + 2 * per_split <= ws_size) NS = 2;
  float* Opart = (float*)alloc((size_t)NS * kPR * kDK * 4);
  float* Mpart = (float*)alloc((size_t)NS * kPR * 4);
  float* Lpart = (float*)alloc((size_t)NS * kPR * 4);

  detect_mask_kernel<<<1, 256, 0, stream>>>(mask, flagp);

  dim3 blk(256);
  proj_kernel<<<dim3(32, 4, 3), blk, 0, stream>>>(query, key_in, value, Wq, Wk, Wv,
                                                  q_ws, k_ws, vt_ws);
  attn_kernel<<<dim3(32, 16, NS), blk, 0, stream>>>(q_ws, k_ws, vt_ws, attnw, mask,
                                                    flagp, Opart, Mpart, Lpart, kS / NS);
  combine_kernel<<<dim3(kPR * kDK / 256), blk, 0, stream>>>(Opart, Mpart, Lpart, x_ws, NS);
  out_kernel<<<dim3(32, 4), blk, 0, stream>>>(x_ws, Wo, (float*)d_out);
}

// Round 3
// 211.567 us; speedup vs baseline: 1.1575x; 1.1575x over previous
//
#include <hip/hip_runtime.h>
#include <math.h>

typedef __bf16 bf16;
typedef __bf16 bf16x8 __attribute__((ext_vector_type(8)));
typedef float f32x4 __attribute__((ext_vector_type(4)));
typedef unsigned int u32;

#define MFMA_BF16(a, b, c) __builtin_amdgcn_mfma_f32_16x16x32_bf16((a), (b), (c), 0, 0, 0)

static constexpr int kB = 2;
static constexpr int kS = 2048;
static constexpr int kD = 512;
static constexpr int kH = 8;
static constexpr int kDK = 64;

// ---------------- mask preprocess: detect dtype + build bitmask ----------------
// bm[b*64 + w] bit j = mask[b*2048 + w*32 + j] (True -> -inf).
__global__ void detect_mask_kernel(const unsigned char* __restrict__ m,
                                   u32* __restrict__ bm) {
  __shared__ int sh;
  const int tid = threadIdx.x;
  if (tid == 0) sh = 0;
  __syncthreads();
  int any = 0;
  for (int i = tid; i < kB * kS; i += 256)
    if ((i & 3) != 0 && m[i] != 0) any = 1;
  if (any) atomicOr(&sh, 1);
  __syncthreads();
  const bool as_bool = (sh != 0);
  for (int wi = tid; wi < kB * kS / 32; wi += 256) {
    u32 word = 0;
    const int base = wi * 32;
    for (int j = 0; j < 32; j++) {
      const bool mv = as_bool ? (m[base + j] != 0) : (((const int*)m)[base + j] != 0);
      word |= (mv ? 1u : 0u) << j;
    }
    bm[wi] = word;
  }
}

// ---------------- helpers ----------------
__device__ __forceinline__ void cvt16(const float* __restrict__ p, bf16x8& v0, bf16x8& v1) {
  const float4 fA = ((const float4*)p)[0];
  const float4 fB = ((const float4*)p)[1];
  const float4 fC = ((const float4*)p)[2];
  const float4 fD = ((const float4*)p)[3];
  v0[0] = (bf16)fA.x; v0[1] = (bf16)fA.y; v0[2] = (bf16)fA.z; v0[3] = (bf16)fA.w;
  v0[4] = (bf16)fB.x; v0[5] = (bf16)fB.y; v0[6] = (bf16)fB.z; v0[7] = (bf16)fB.w;
  v1[0] = (bf16)fC.x; v1[1] = (bf16)fC.y; v1[2] = (bf16)fC.z; v1[3] = (bf16)fC.w;
  v1[4] = (bf16)fD.x; v1[5] = (bf16)fD.y; v1[6] = (bf16)fD.z; v1[7] = (bf16)fD.w;
}

// ---------------- GEMM: C[m][n] = sum_k A[m][k] * W[n][k] ----------------
template <bool A_IS_F32>
__device__ __forceinline__ void gemm_body(const void* __restrict__ Aptr,
                                          const float* __restrict__ Wptr,
                                          void* __restrict__ dst, const int mode) {
  __shared__ bf16 As[128][40];
  __shared__ bf16 Bs[128][40];

  const int tid = threadIdx.x;
  const int lane = tid & 63;
  const int w = tid >> 6;
  const int wr = w >> 1, wc = w & 1;
  const int l16 = lane & 15, g = lane >> 4;

  const int m_tile = blockIdx.x * 128;
  const int n_tile = blockIdx.y * 128;

  f32x4 acc[4][4] = {};

  const int sr = tid >> 1;
  const int sc = (tid & 1) * 16;

  for (int k0 = 0; k0 < kD; k0 += 32) {
    if constexpr (A_IS_F32) {
      const float* ap = (const float*)Aptr + (size_t)(m_tile + sr) * kD + k0 + sc;
      bf16x8 v0, v1;
      cvt16(ap, v0, v1);
      *(bf16x8*)&As[sr][sc] = v0;
      *(bf16x8*)&As[sr][sc + 8] = v1;
    } else {
      const bf16* ap = (const bf16*)Aptr + (size_t)(m_tile + sr) * kD + k0 + sc;
      *(bf16x8*)&As[sr][sc] = *(const bf16x8*)ap;
      *(bf16x8*)&As[sr][sc + 8] = *(const bf16x8*)(ap + 8);
    }
    {
      const float* bp = Wptr + (size_t)(n_tile + sr) * kD + k0 + sc;
      bf16x8 v0, v1;
      cvt16(bp, v0, v1);
      *(bf16x8*)&Bs[sr][sc] = v0;
      *(bf16x8*)&Bs[sr][sc + 8] = v1;
    }
    __syncthreads();

    bf16x8 a[4], bfr[4];
    #pragma unroll
    for (int i = 0; i < 4; i++)
      a[i] = *(const bf16x8*)&As[wr * 64 + i * 16 + l16][g * 8];
    #pragma unroll
    for (int i = 0; i < 4; i++)
      bfr[i] = *(const bf16x8*)&Bs[wc * 64 + i * 16 + l16][g * 8];
    #pragma unroll
    for (int mi = 0; mi < 4; mi++)
      #pragma unroll
      for (int ni = 0; ni < 4; ni++)
        acc[mi][ni] = MFMA_BF16(a[mi], bfr[ni], acc[mi][ni]);
    __syncthreads();
  }

  #pragma unroll
  for (int mi = 0; mi < 4; mi++) {
    #pragma unroll
    for (int ni = 0; ni < 4; ni++) {
      const int gm0 = m_tile + wr * 64 + mi * 16 + g * 4;
      const int gn = n_tile + wc * 64 + ni * 16 + l16;
      #pragma unroll
      for (int q = 0; q < 4; q++) {
        const int gm = gm0 + q;
        const float v = acc[mi][ni][q];
        if (mode == 3) {
          ((float*)dst)[(size_t)gm * kD + gn] = v;
        } else {
          const int bi = gm >> 11;
          const int s = gm & (kS - 1);
          const int h = gn >> 6;
          const int dk = gn & (kDK - 1);
          if (mode == 2)
            ((bf16*)dst)[(((size_t)bi * kH + h) * kDK + dk) * kS + s] = (bf16)v;
          else
            ((bf16*)dst)[(((size_t)bi * kH + h) * kS + s) * kDK + dk] = (bf16)v;
        }
      }
    }
  }
}

__global__ __launch_bounds__(256) void proj_kernel(
    const float* __restrict__ q, const float* __restrict__ k, const float* __restrict__ v,
    const float* __restrict__ Wq, const float* __restrict__ Wk, const float* __restrict__ Wv,
    bf16* __restrict__ qw, bf16* __restrict__ kw, bf16* __restrict__ vtw) {
  const int z = blockIdx.z;
  const float* A = (z == 0) ? q : (z == 1) ? k : v;
  const float* W = (z == 0) ? Wq : (z == 1) ? Wk : Wv;
  bf16* dstp = (z == 0) ? qw : (z == 1) ? kw : vtw;
  gemm_body<true>(A, W, dstp, (z == 2) ? 2 : 0);
}

__global__ __launch_bounds__(256) void out_kernel(const bf16* __restrict__ x,
                                                  const float* __restrict__ Wo,
                                                  float* __restrict__ out) {
  gemm_body<false>(x, Wo, out, 3);
}

// ---------------- attention (swapped-operand, register double-buffer) --------
// 1-D grid of 512 blocks, XCD-grouped: each XCD owns 2 bh values so K/V stay
// L2-resident under the nontemporal bias stream. No block barriers; each wave
// owns 16 q-rows. Bias+K for tile t+1 issue while tile t computes.
__global__ __launch_bounds__(256, 2) void attn_kernel(
    const bf16* __restrict__ qw, const bf16* __restrict__ kw,
    const bf16* __restrict__ vt, const float* __restrict__ bias,
    const u32* __restrict__ bmask, bf16* __restrict__ xw) {
  __shared__ u32 Ps[4][16][36];  // per-wave packed P^T rows: [q][k/2], pad 36

  const int tid = threadIdx.x;
  const int lane = tid & 63;
  const int w = tid >> 6;
  const int l16 = lane & 15, g = lane >> 4;

  // XCD swizzle: bid%8 = XCD; give each XCD 2 bh values, all 32 q-blocks.
  const int bid = blockIdx.x;
  const int xcd = bid & 7;
  const int idx = bid >> 3;              // 0..63
  const int bh = xcd * 2 + (idx >> 5);   // 0..15
  const int qb = idx & 31;               // 0..31
  const int b = bh >> 3;
  const int hh = bh & 7;
  const int qr0 = (qb * 4 + w) * 16;

  // Q as B operand: col=q=l16, k = g*8+j
  const bf16* qrow = qw + ((size_t)bh * kS + qr0 + l16) * kDK;
  const bf16x8 aq0 = *(const bf16x8*)(qrow + g * 8);
  const bf16x8 aq1 = *(const bf16x8*)(qrow + 32 + g * 8);

  const float* brow = bias + ((size_t)bh * kS + qr0 + l16) * kS;  // bias row q=l16
  const bf16* kbase = kw + (size_t)bh * kS * kDK;
  const bf16* vbase = vt + (size_t)bh * kDK * kS;
  const u32* bmb = bmask + b * (kS / 32);

  f32x4 o[4] = {};  // O^T: row d = ni*16+g*4+r, col q = l16
  float m_run = -__builtin_inff();
  float l_run = 0.f;

  auto load_kf = [&](bf16x8 (&kf)[4][2], int k0) {
    #pragma unroll
    for (int nf = 0; nf < 4; nf++) {
      const bf16* kp = kbase + (size_t)(k0 + nf * 16 + l16) * kDK + g * 8;
      kf[nf][0] = *(const bf16x8*)kp;
      kf[nf][1] = *(const bf16x8*)(kp + 32);
    }
  };
  auto load_bias4 = [&](f32x4 (&bv)[4], int k0) {
    #pragma unroll
    for (int nf = 0; nf < 4; nf++)
      bv[nf] = __builtin_nontemporal_load((const f32x4*)(brow + k0 + nf * 16 + g * 4));
  };

  auto phase = [&](bf16x8 (&kc)[4][2], f32x4 (&bc)[4], int k0,
                   bf16x8 (&kn)[4][2], f32x4 (&bn)[4], int kpre) {
    // ---- issue next tile's HBM-critical loads first ----
    load_kf(kn, kpre);
    load_bias4(bn, kpre);
    // ---- V for current tile (L2; consumed after softmax) ----
    bf16x8 vf[2][4];
    #pragma unroll
    for (int kb = 0; kb < 2; kb++)
      #pragma unroll
      for (int ni = 0; ni < 4; ni++)
        vf[kb][ni] = *(const bf16x8*)(vbase + (size_t)(ni * 16 + l16) * kS + k0 + kb * 32 + g * 8);

    const u32 w0 = bmb[k0 >> 5];
    const u32 w1 = bmb[(k0 >> 5) + 1];

    // ---- QK^T swapped: C[k][q] ----
    f32x4 sf[4];
    __builtin_amdgcn_s_setprio(1);
    #pragma unroll
    for (int nf = 0; nf < 4; nf++) {
      f32x4 z = {};
      z = MFMA_BF16(kc[nf][0], aq0, z);
      z = MFMA_BF16(kc[nf][1], aq1, z);
      sf[nf] = z;
    }
    __builtin_amdgcn_s_setprio(0);

    // ---- scores: scale, mask, bias; per-lane online softmax (q = l16) ----
    float p[4][4];
    float tmax = -__builtin_inff();
    #pragma unroll
    for (int nf = 0; nf < 4; nf++) {
      const u32 wsel = (nf < 2) ? w0 : w1;
      #pragma unroll
      for (int r = 0; r < 4; r++) {
        float sv = sf[nf][r] * 0.125f - bc[nf][r];
        const int bp = (nf & 1) * 16 + g * 4 + r;
        if ((wsel >> bp) & 1) sv = -__builtin_inff();
        p[nf][r] = sv;
        tmax = fmaxf(tmax, sv);
      }
    }
    tmax = fmaxf(tmax, __shfl_xor(tmax, 16, 64));
    tmax = fmaxf(tmax, __shfl_xor(tmax, 32, 64));

    const float mnew = fmaxf(m_run, tmax);
    const float scale = (m_run == -__builtin_inff()) ? 0.f : __expf(m_run - mnew);
    const float mexp = (mnew == -__builtin_inff()) ? 0.f : mnew;
    float psum = 0.f;
    #pragma unroll
    for (int nf = 0; nf < 4; nf++)
      #pragma unroll
      for (int r = 0; r < 4; r++) {
        const float pv = __expf(p[nf][r] - mexp);
        p[nf][r] = pv;
        psum += pv;
      }
    psum += __shfl_xor(psum, 16, 64);
    psum += __shfl_xor(psum, 32, 64);
    m_run = mnew;
    l_run = l_run * scale + psum;
    #pragma unroll
    for (int ni = 0; ni < 4; ni++) o[ni] *= scale;

    // ---- P^T pack to LDS: row q=l16, u32 col = k/2 ----
    #pragma unroll
    for (int nf = 0; nf < 4; nf++) {
      union { bf16 h[2]; u32 u; } c0, c1;
      c0.h[0] = (bf16)p[nf][0]; c0.h[1] = (bf16)p[nf][1];
      c1.h[0] = (bf16)p[nf][2]; c1.h[1] = (bf16)p[nf][3];
      Ps[w][l16][nf * 8 + g * 2] = c0.u;
      Ps[w][l16][nf * 8 + g * 2 + 1] = c1.u;
    }
    asm volatile("s_waitcnt lgkmcnt(0)" ::: "memory");

    // ---- PV: O^T += V^T * P^T ----
    __builtin_amdgcn_s_setprio(1);
    #pragma unroll
    for (int kb = 0; kb < 2; kb++) {
      const bf16x8 pb = *(const bf16x8*)&Ps[w][l16][kb * 16 + g * 4];
      #pragma unroll
      for (int ni = 0; ni < 4; ni++)
        o[ni] = MFMA_BF16(vf[kb][ni], pb, o[ni]);
    }
    __builtin_amdgcn_s_setprio(0);
  };

  bf16x8 kA[4][2], kB[4][2];
  f32x4 bA[4], bB[4];
  load_kf(kA, 0);
  load_bias4(bA, 0);

  for (int t = 0; t < 32; t += 2) {
    phase(kA, bA, t * 64, kB, bB, ((t + 1) & 31) * 64);
    phase(kB, bB, (t + 1) * 64, kA, bA, ((t + 2) & 31) * 64);
  }

  // ---- epilogue: normalize, write x[b][q][h*64+d] bf16 ----
  const float inv = (l_run > 0.f) ? 1.f / l_run : 0.f;
  bf16* dstp = xw + ((size_t)b * kS + qr0 + l16) * kD + hh * kDK;
  #pragma unroll
  for (int ni = 0; ni < 4; ni++) {
    union { bf16 h[2]; u32 u; } c0, c1;
    c0.h[0] = (bf16)(o[ni][0] * inv); c0.h[1] = (bf16)(o[ni][1] * inv);
    c1.h[0] = (bf16)(o[ni][2] * inv); c1.h[1] = (bf16)(o[ni][3] * inv);
    *(u32*)&dstp[ni * 16 + g * 4] = c0.u;
    *(u32*)&dstp[ni * 16 + g * 4 + 2] = c1.u;
  }
}

extern "C" void kernel_launch(void* const* d_in, const int* in_sizes, int n_in,
                              void* d_out, int out_size, void* d_ws, size_t ws_size,
                              hipStream_t stream) {
  (void)in_sizes; (void)n_in; (void)out_size; (void)ws_size;
  const float* query = (const float*)d_in[0];
  const float* key_in = (const float*)d_in[1];
  const float* value = (const float*)d_in[2];
  const float* attnw = (const float*)d_in[3];
  const unsigned char* mask = (const unsigned char*)d_in[4];
  const float* Wq = (const float*)d_in[5];
  const float* Wk = (const float*)d_in[6];
  const float* Wv = (const float*)d_in[7];
  const float* Wo = (const float*)d_in[8];

  const size_t nqkv = (size_t)kB * kH * kS * kDK;  // 2M elems
  size_t off = 0;
  auto alloc = [&](size_t bytes) {
    void* p = (char*)d_ws + off;
    off = (off + bytes + 255) & ~(size_t)255;
    return p;
  };
  u32* bm = (u32*)alloc(kB * kS / 32 * 4);
  bf16* q_ws = (bf16*)alloc(nqkv * 2);
  bf16* k_ws = (bf16*)alloc(nqkv * 2);
  bf16* vt_ws = (bf16*)alloc(nqkv * 2);
  bf16* x_ws = (bf16*)alloc((size_t)kB * kS * kD * 2);

  detect_mask_kernel<<<1, 256, 0, stream>>>(mask, bm);

  dim3 blk(256);
  proj_kernel<<<dim3(32, 4, 3), blk, 0, stream>>>(query, key_in, value, Wq, Wk, Wv,
                                                  q_ws, k_ws, vt_ws);
  attn_kernel<<<dim3(512), blk, 0, stream>>>(q_ws, k_ws, vt_ws, attnw, bm, x_ws);
  out_kernel<<<dim3(32, 4), blk, 0, stream>>>(x_ws, Wo, (float*)d_out);
}